// Round 2
// baseline (1205.076 us; speedup 1.0000x reference)
//
#include <hip/hip_runtime.h>
#include <hip/hip_bf16.h>

// Problem constants (from reference)
#define NN 50000
#define EE 800000
#define GG 64
#define RR 3
#define CC 10
// Y layout per node (832 cols): [0:128 fs | 128:192 xs | 192:384 xr(r=0..2) |
//                                384:768 fm(r, beta|gamma) | 768:832 xp]
// After post_k, cols 0:64 hold skip_out (relu(fs_gamma*xs+fs_beta)).

__device__ inline float leaky02(float x) { return x > 0.f ? x : 0.2f * x; }

__device__ inline void atomicMaxF(float* addr, float v) {
  if (v >= 0.f) atomicMax((int*)addr, __float_as_int(v));
  else          atomicMin((unsigned int*)addr, __float_as_uint(v));
}

// ---- pack all node weights into Wcat (64 x 832) -------------------------
__global__ void pack_w_k(const float* __restrict__ skip_film_W,
                         const float* __restrict__ skip_W,
                         const float* __restrict__ film_lin_W,
                         const float* __restrict__ film_film_W,
                         const float* __restrict__ gat_W,
                         float* __restrict__ Wcat) {
  int idx = blockIdx.x * blockDim.x + threadIdx.x;
  if (idx >= 64 * 832) return;
  int k = idx / 832, c = idx % 832;
  float v;
  if (c < 128)      v = skip_film_W[k * 128 + c];
  else if (c < 192) v = skip_W[k * 64 + (c - 128)];
  else if (c < 384) { int cc = c - 192, r = cc >> 6, h = cc & 63;
                      v = film_lin_W[(r * 64 + k) * 64 + h]; }
  else if (c < 768) { int cc = c - 384, r = cc >> 7, j = cc & 127;
                      v = film_film_W[(r * 64 + k) * 128 + j]; }
  else              v = gat_W[k * 64 + (c - 768)];
  Wcat[idx] = v;
}

// ---- X(50000x64) @ Wcat(64x832) -> Y ------------------------------------
__global__ __launch_bounds__(256) void gemm_k(const float* __restrict__ X,
                                              const float* __restrict__ W,
                                              float* __restrict__ Y) {
  __shared__ __align__(16) float As[64][65];   // +1 pad: row-broadcast reads
  __shared__ __align__(16) float Bs[64][128];
  const int tid = threadIdx.x;
  const int row0 = blockIdx.x * 64;
  const int col0 = blockIdx.y * 128;

  // load A tile 64x64 (float4 per chunk)
  #pragma unroll
  for (int s = 0; s < 4; s++) {
    int q = s * 256 + tid;           // 0..1023 float4 chunks
    int r = q >> 4;
    int c4 = (q & 15) << 2;
    int gr = row0 + r;
    float4 v = make_float4(0.f, 0.f, 0.f, 0.f);
    if (gr < NN) v = *reinterpret_cast<const float4*>(X + (size_t)gr * 64 + c4);
    As[r][c4 + 0] = v.x; As[r][c4 + 1] = v.y;
    As[r][c4 + 2] = v.z; As[r][c4 + 3] = v.w;
  }
  // load B tile 64x128
  #pragma unroll
  for (int s = 0; s < 8; s++) {
    int q = s * 256 + tid;           // 0..2047 float4 chunks
    int r = q >> 5;
    int c4 = (q & 31) << 2;
    int gc = col0 + c4;
    float4 v = make_float4(0.f, 0.f, 0.f, 0.f);
    if (gc + 3 < 832) v = *reinterpret_cast<const float4*>(W + (size_t)r * 832 + gc);
    *reinterpret_cast<float4*>(&Bs[r][c4]) = v;
  }
  __syncthreads();

  const int tx = tid & 15, ty = tid >> 4;
  float acc[4][8] = {};
  #pragma unroll 8
  for (int k = 0; k < 64; k++) {
    float a0 = As[ty * 4 + 0][k], a1 = As[ty * 4 + 1][k];
    float a2 = As[ty * 4 + 2][k], a3 = As[ty * 4 + 3][k];
    const float4* bp = reinterpret_cast<const float4*>(&Bs[k][tx * 8]);
    float4 b0 = bp[0], b1 = bp[1];
    float bb[8] = {b0.x, b0.y, b0.z, b0.w, b1.x, b1.y, b1.z, b1.w};
    #pragma unroll
    for (int j = 0; j < 8; j++) {
      acc[0][j] += a0 * bb[j]; acc[1][j] += a1 * bb[j];
      acc[2][j] += a2 * bb[j]; acc[3][j] += a3 * bb[j];
    }
  }
  #pragma unroll
  for (int i = 0; i < 4; i++) {
    int gr = row0 + ty * 4 + i;
    if (gr >= NN) continue;
    int gc = col0 + tx * 8;
    if (gc + 7 < 832) {
      float4 o0 = {acc[i][0], acc[i][1], acc[i][2], acc[i][3]};
      float4 o1 = {acc[i][4], acc[i][5], acc[i][6], acc[i][7]};
      *reinterpret_cast<float4*>(Y + (size_t)gr * 832 + gc) = o0;
      *reinterpret_cast<float4*>(Y + (size_t)gr * 832 + gc + 4) = o1;
    }
  }
}

// ---- per-node post: biases, skip_out, attention scalars, m init ----------
__global__ __launch_bounds__(256) void post_k(float* __restrict__ Y,
    const float* __restrict__ film_film_b, const float* __restrict__ skip_film_b,
    const float* __restrict__ att_src, const float* __restrict__ att_dst,
    float* __restrict__ m, float* __restrict__ as_, float* __restrict__ ad_) {
  int n = blockIdx.x * 4 + (threadIdx.x >> 6);
  if (n >= NN) return;
  int h = threadIdx.x & 63;
  float* y = Y + (size_t)n * 832;
  #pragma unroll
  for (int r = 0; r < RR; r++) {
    y[384 + r * 128 + h]      += film_film_b[r * 128 + h];
    y[448 + r * 128 + h]      += film_film_b[r * 128 + 64 + h];
  }
  float fsb = y[h]       + skip_film_b[h];
  float fsg = y[64 + h]  + skip_film_b[64 + h];
  float xs  = y[128 + h];
  float so  = fmaxf(fsg * xs + fsb, 0.f);
  float xph = y[768 + h];
  float pa = xph * att_src[h], pd = xph * att_dst[h];
  #pragma unroll
  for (int off = 32; off > 0; off >>= 1) {
    pa += __shfl_xor(pa, off);
    pd += __shfl_xor(pd, off);
  }
  y[h] = so;                        // overwrite fs beta col with skip_out
  if (h == 0) {
    as_[n] = pa; ad_[n] = pd;
    m[n] = leaky02(pa + pd);        // self-loop energy seeds the max
  }
}

// ---- edge pass 1: counts + softmax max ----------------------------------
__global__ void edge_scalar_k(const int* __restrict__ ei, const int* __restrict__ et,
                              const float* __restrict__ as_, const float* __restrict__ ad_,
                              int* __restrict__ cnt, float* __restrict__ m) {
  int e = blockIdx.x * blockDim.x + threadIdx.x;
  if (e >= EE) return;
  int src = ei[e], dst = ei[EE + e], t = et[e];
  atomicAdd(&cnt[dst * RR + t], 1);
  atomicMaxF(&m[dst], leaky02(as_[src] + ad_[dst]));
}

// ---- edge pass 2: FiLM messages + unnormalized GAT accumulation ---------
__global__ __launch_bounds__(256) void edge_vec_k(const int* __restrict__ ei,
    const int* __restrict__ etp, const float* __restrict__ Y,
    const int* __restrict__ cnt, const float* __restrict__ m,
    const float* __restrict__ as_, const float* __restrict__ ad_,
    float* __restrict__ agg, float* __restrict__ S, float* __restrict__ denom) {
  int e = blockIdx.x * 4 + (threadIdx.x >> 6);
  if (e >= EE) return;
  int h = threadIdx.x & 63;
  int src = ei[e], dst = ei[EE + e], t = etp[e];
  const float* ys = Y + (size_t)src * 832;
  const float* yd = Y + (size_t)dst * 832;
  // FiLM
  float xr  = ys[192 + t * 64 + h];
  float bet = yd[384 + t * 128 + h];
  float gam = yd[448 + t * 128 + h];
  int c = cnt[dst * RR + t];
  float invd = 1.0f / (float)(c > 1 ? c : 1);
  float msg = fmaxf(gam * xr + bet, 0.f) * invd;
  atomicAdd(&agg[(size_t)dst * 64 + h], msg);
  // GAT (unnormalized; normalize in feats_k)
  float ev = leaky02(as_[src] + ad_[dst]);
  float w = expf(ev - m[dst]);
  atomicAdd(&S[(size_t)dst * 64 + h], w * ys[768 + h]);
  if (h == 0) atomicAdd(&denom[dst], w);
}

// ---- per-node feats + graph boundary detection --------------------------
__global__ __launch_bounds__(256) void feats_k(const float* __restrict__ Y,
    const float* __restrict__ agg, const float* __restrict__ S,
    const float* __restrict__ denom, const float* __restrict__ m,
    const float* __restrict__ as_, const float* __restrict__ ad_,
    const float* __restrict__ gat_b, const int* __restrict__ gb,
    float* __restrict__ feats, int* __restrict__ gstart, int* __restrict__ gend) {
  int n = blockIdx.x * 4 + (threadIdx.x >> 6);
  if (n >= NN) return;
  int h = threadIdx.x & 63;
  const float* y = Y + (size_t)n * 832;
  float o1 = fmaxf(y[h] + agg[(size_t)n * 64 + h], 0.f);
  float es = leaky02(as_[n] + ad_[n]);
  float wself = expf(es - m[n]);
  float den = denom[n] + wself;
  float o2 = fmaxf((S[(size_t)n * 64 + h] + wself * y[768 + h]) / den + gat_b[h], 0.f);
  feats[(size_t)n * 128 + h]      = o1;
  feats[(size_t)n * 128 + 64 + h] = o2;
  if (h == 0) {
    int g = gb[n];
    atomicMin(&gstart[g], n);
    atomicMax(&gend[g], n);
  }
}

// ---- per-graph max+mean pooling (graph_batch sorted => contiguous) ------
__global__ __launch_bounds__(128) void pool_k(const float* __restrict__ feats,
    const int* __restrict__ gstart, const int* __restrict__ gend,
    float* __restrict__ pooled) {
  int g = blockIdx.x, f = threadIdx.x;
  int s = gstart[g], e = gend[g];
  float mx = -3.0e38f, sm = 0.f;
  int c = 0;
  if (s <= e && s < NN) {
    c = e - s + 1;
    for (int n = s; n <= e; n++) {
      float v = feats[(size_t)n * 128 + f];
      mx = fmaxf(mx, v);
      sm += v;
    }
  }
  pooled[g * 256 + f]       = (c > 0) ? mx : 0.f;
  pooled[g * 256 + 128 + f] = sm / (float)(c > 1 ? c : 1);
}

// ---- head MLP + log_softmax (fp32 output, matching reference dtype) -----
__global__ __launch_bounds__(64) void head_k(const float* __restrict__ pooled,
    const float* __restrict__ lin_W, const float* __restrict__ lin_b,
    const float* __restrict__ fc_W, const float* __restrict__ fc_b,
    float* __restrict__ out) {
  __shared__ float p[256];
  __shared__ float hid[64];
  __shared__ float lg[CC];
  __shared__ float lse;
  int g = blockIdx.x, t = threadIdx.x;
  for (int i = t; i < 256; i += 64) p[i] = pooled[g * 256 + i];
  __syncthreads();
  float acc = lin_b[t];
  for (int k = 0; k < 256; k++) acc += p[k] * lin_W[k * 64 + t];
  hid[t] = fmaxf(acc, 0.f);
  __syncthreads();
  if (t < CC) {
    float a = fc_b[t];
    for (int k = 0; k < 64; k++) a += hid[k] * fc_W[k * CC + t];
    lg[t] = a;
  }
  __syncthreads();
  if (t == 0) {
    float mx = lg[0];
    for (int i = 1; i < CC; i++) mx = fmaxf(mx, lg[i]);
    float s = 0.f;
    for (int i = 0; i < CC; i++) s += expf(lg[i] - mx);
    lse = mx + logf(s);
  }
  __syncthreads();
  if (t < CC) out[g * CC + t] = lg[t] - lse;
}

extern "C" void kernel_launch(void* const* d_in, const int* in_sizes, int n_in,
                              void* d_out, int out_size, void* d_ws, size_t ws_size,
                              hipStream_t stream) {
  const float* x            = (const float*)d_in[0];
  const int*   edge_index   = (const int*)d_in[1];
  const int*   edge_type    = (const int*)d_in[2];
  const int*   graph_batch  = (const int*)d_in[3];
  const float* film_lin_W   = (const float*)d_in[4];
  const float* film_film_W  = (const float*)d_in[5];
  const float* film_film_b  = (const float*)d_in[6];
  const float* skip_W       = (const float*)d_in[7];
  const float* skip_film_W  = (const float*)d_in[8];
  const float* skip_film_b  = (const float*)d_in[9];
  const float* gat_W        = (const float*)d_in[10];
  const float* att_src      = (const float*)d_in[11];
  const float* att_dst      = (const float*)d_in[12];
  const float* gat_b        = (const float*)d_in[13];
  const float* lin_W        = (const float*)d_in[14];
  const float* lin_b        = (const float*)d_in[15];
  const float* fc_W         = (const float*)d_in[16];
  const float* fc_b         = (const float*)d_in[17];
  float* out                = (float*)d_out;   // reference output dtype = fp32

  float* ws = (float*)d_ws;
  const size_t N = NN, G = GG;
  size_t oY      = 0;                         // N*832
  size_t oAgg    = N * 832;                   // N*64
  size_t oS      = oAgg + N * 64;             // N*64
  size_t oDen    = oS + N * 64;               // N
  size_t oCnt    = oDen + N;                  // N*3 (int)
  size_t oGend   = oCnt + N * 3;              // G (int, zero init)
  size_t oGstart = oGend + G;                 // G (int, 0x7f init)
  size_t oM      = oGstart + G;               // N
  size_t oAs     = oM + N;                    // N
  size_t oAd     = oAs + N;                   // N
  size_t oW      = oAd + N;                   // 64*832
  size_t oFeats  = oW + 64 * 832;             // N*128
  size_t oPooled = oFeats + N * 128;          // G*256

  float* Y      = ws + oY;
  float* agg    = ws + oAgg;
  float* S      = ws + oS;
  float* denom  = ws + oDen;
  int*   cnt    = (int*)(ws + oCnt);
  int*   gend   = (int*)(ws + oGend);
  int*   gstart = (int*)(ws + oGstart);
  float* m      = ws + oM;
  float* as_    = ws + oAs;
  float* ad_    = ws + oAd;
  float* Wcat   = ws + oW;
  float* feats  = ws + oFeats;
  float* pooled = ws + oPooled;

  // zero agg, S, denom, cnt, gend in one memset; gstart -> large int
  size_t zeroBytes = (oGend + G - oAgg) * sizeof(float);
  hipMemsetAsync(agg, 0, zeroBytes, stream);
  hipMemsetAsync(gstart, 0x7f, G * sizeof(int), stream);

  pack_w_k<<<(64 * 832 + 255) / 256, 256, 0, stream>>>(
      skip_film_W, skip_W, film_lin_W, film_film_W, gat_W, Wcat);
  gemm_k<<<dim3((NN + 63) / 64, 7), 256, 0, stream>>>(x, Wcat, Y);
  post_k<<<(NN + 3) / 4, 256, 0, stream>>>(Y, film_film_b, skip_film_b,
                                           att_src, att_dst, m, as_, ad_);
  edge_scalar_k<<<(EE + 255) / 256, 256, 0, stream>>>(edge_index, edge_type,
                                                      as_, ad_, cnt, m);
  edge_vec_k<<<(EE + 3) / 4, 256, 0, stream>>>(edge_index, edge_type, Y, cnt,
                                               m, as_, ad_, agg, S, denom);
  feats_k<<<(NN + 3) / 4, 256, 0, stream>>>(Y, agg, S, denom, m, as_, ad_,
                                            gat_b, graph_batch, feats, gstart, gend);
  pool_k<<<GG, 128, 0, stream>>>(feats, gstart, gend, pooled);
  head_k<<<GG, 64, 0, stream>>>(pooled, lin_W, lin_b, fc_W, fc_b, out);
}

// Round 3
// 833.698 us; speedup vs baseline: 1.4455x; 1.4455x over previous
//
#include <hip/hip_runtime.h>
#include <hip/hip_bf16.h>

// Problem constants (from reference)
#define NN 50000
#define EE 800000
#define GG 64
#define RR 3
#define CC 10
// Y layout per node (832 cols): [0:128 fs | 128:192 xs | 192:384 xr(r=0..2) |
//                                384:768 fm(r, beta|gamma) | 768:832 xp]
// Biases are folded into the GEMM epilogue via a packed 832-length bias vec.
// After post_k, col 0:64 holds skip_out.

__device__ inline float leaky02(float x) { return x > 0.f ? x : 0.2f * x; }

// valid for non-negative floats only (int compare == float compare there)
__device__ inline void atomicMaxFPos(float* addr, float v) {
  atomicMax((int*)addr, __float_as_int(v));
}

// ---- pack node weights into Wcat (64 x 832) + bias vec (832) ------------
__global__ void pack_w_k(const float* __restrict__ skip_film_W,
                         const float* __restrict__ skip_W,
                         const float* __restrict__ film_lin_W,
                         const float* __restrict__ film_film_W,
                         const float* __restrict__ gat_W,
                         const float* __restrict__ skip_film_b,
                         const float* __restrict__ film_film_b,
                         float* __restrict__ Wcat, float* __restrict__ bias) {
  int idx = blockIdx.x * blockDim.x + threadIdx.x;
  if (idx >= 64 * 832 + 832) return;
  if (idx >= 64 * 832) {                 // bias vector
    int c = idx - 64 * 832;
    float b = 0.f;
    if (c < 128) b = skip_film_b[c];
    else if (c >= 384 && c < 768) b = film_film_b[c - 384];
    bias[c] = b;
    return;
  }
  int k = idx / 832, c = idx % 832;
  float v;
  if (c < 128)      v = skip_film_W[k * 128 + c];
  else if (c < 192) v = skip_W[k * 64 + (c - 128)];
  else if (c < 384) { int cc = c - 192, r = cc >> 6, h = cc & 63;
                      v = film_lin_W[(r * 64 + k) * 64 + h]; }
  else if (c < 768) { int cc = c - 384, r = cc >> 7, j = cc & 127;
                      v = film_film_W[(r * 64 + k) * 128 + j]; }
  else              v = gat_W[k * 64 + (c - 768)];
  Wcat[idx] = v;
}

// ---- X(50000x64) @ Wcat(64x832) + bias -> Y -----------------------------
__global__ __launch_bounds__(256) void gemm_k(const float* __restrict__ X,
                                              const float* __restrict__ W,
                                              const float* __restrict__ bias,
                                              float* __restrict__ Y) {
  __shared__ __align__(16) float As[64][65];
  __shared__ __align__(16) float Bs[64][128];
  const int tid = threadIdx.x;
  const int row0 = blockIdx.x * 64;
  const int col0 = blockIdx.y * 128;

  #pragma unroll
  for (int s = 0; s < 4; s++) {
    int q = s * 256 + tid;
    int r = q >> 4;
    int c4 = (q & 15) << 2;
    int gr = row0 + r;
    float4 v = make_float4(0.f, 0.f, 0.f, 0.f);
    if (gr < NN) v = *reinterpret_cast<const float4*>(X + (size_t)gr * 64 + c4);
    As[r][c4 + 0] = v.x; As[r][c4 + 1] = v.y;
    As[r][c4 + 2] = v.z; As[r][c4 + 3] = v.w;
  }
  #pragma unroll
  for (int s = 0; s < 8; s++) {
    int q = s * 256 + tid;
    int r = q >> 5;
    int c4 = (q & 31) << 2;
    int gc = col0 + c4;
    float4 v = make_float4(0.f, 0.f, 0.f, 0.f);
    if (gc + 3 < 832) v = *reinterpret_cast<const float4*>(W + (size_t)r * 832 + gc);
    *reinterpret_cast<float4*>(&Bs[r][c4]) = v;
  }
  __syncthreads();

  const int tx = tid & 15, ty = tid >> 4;
  float acc[4][8] = {};
  #pragma unroll 8
  for (int k = 0; k < 64; k++) {
    float a0 = As[ty * 4 + 0][k], a1 = As[ty * 4 + 1][k];
    float a2 = As[ty * 4 + 2][k], a3 = As[ty * 4 + 3][k];
    const float4* bp = reinterpret_cast<const float4*>(&Bs[k][tx * 8]);
    float4 b0 = bp[0], b1 = bp[1];
    float bb[8] = {b0.x, b0.y, b0.z, b0.w, b1.x, b1.y, b1.z, b1.w};
    #pragma unroll
    for (int j = 0; j < 8; j++) {
      acc[0][j] += a0 * bb[j]; acc[1][j] += a1 * bb[j];
      acc[2][j] += a2 * bb[j]; acc[3][j] += a3 * bb[j];
    }
  }
  int gc = col0 + tx * 8;
  if (gc + 7 < 832) {
    float4 bv0 = *reinterpret_cast<const float4*>(bias + gc);
    float4 bv1 = *reinterpret_cast<const float4*>(bias + gc + 4);
    #pragma unroll
    for (int i = 0; i < 4; i++) {
      int gr = row0 + ty * 4 + i;
      if (gr >= NN) continue;
      float4 o0 = {acc[i][0] + bv0.x, acc[i][1] + bv0.y,
                   acc[i][2] + bv0.z, acc[i][3] + bv0.w};
      float4 o1 = {acc[i][4] + bv1.x, acc[i][5] + bv1.y,
                   acc[i][6] + bv1.z, acc[i][7] + bv1.w};
      *reinterpret_cast<float4*>(Y + (size_t)gr * 832 + gc) = o0;
      *reinterpret_cast<float4*>(Y + (size_t)gr * 832 + gc + 4) = o1;
    }
  }
}

// ---- per-node post: skip_out + attention scalars ------------------------
__global__ __launch_bounds__(256) void post_k(float* __restrict__ Y,
    const float* __restrict__ att_src, const float* __restrict__ att_dst,
    float* __restrict__ as_, float* __restrict__ ad_) {
  int n = blockIdx.x * 4 + (threadIdx.x >> 6);
  if (n >= NN) return;
  int h = threadIdx.x & 63;
  float* y = Y + (size_t)n * 832;
  float fsb = y[h];          // bias already added in gemm
  float fsg = y[64 + h];
  float xs  = y[128 + h];
  float so  = fmaxf(fsg * xs + fsb, 0.f);
  float xph = y[768 + h];
  float pa = xph * att_src[h], pd = xph * att_dst[h];
  #pragma unroll
  for (int off = 32; off > 0; off >>= 1) {
    pa += __shfl_xor(pa, off);
    pd += __shfl_xor(pd, off);
  }
  y[h] = so;
  if (h == 0) { as_[n] = pa; ad_[n] = pd; }
}

// ---- CSR build: count ----------------------------------------------------
__global__ void count_k(const int* __restrict__ ei, int* __restrict__ deg) {
  int e = blockIdx.x * blockDim.x + threadIdx.x;
  if (e >= EE) return;
  atomicAdd(&deg[ei[EE + e]], 1);
}

// ---- CSR build: exclusive scan over 50000 (single block) ----------------
#define SCAN_PER 49
__global__ __launch_bounds__(1024) void scan_k(const int* __restrict__ deg,
                                               int* __restrict__ off) {
  __shared__ int part[1024];
  int t = threadIdx.x;
  int base = t * SCAN_PER;
  int s = 0;
  for (int i = 0; i < SCAN_PER; i++) {
    int idx = base + i;
    if (idx < NN) s += deg[idx];
  }
  part[t] = s;
  __syncthreads();
  for (int ofs = 1; ofs < 1024; ofs <<= 1) {
    int u = 0;
    if (t >= ofs) u = part[t - ofs];
    __syncthreads();
    part[t] += u;
    __syncthreads();
  }
  int run = part[t] - s;   // exclusive prefix
  for (int i = 0; i < SCAN_PER; i++) {
    int idx = base + i;
    if (idx < NN) { off[idx] = run; run += deg[idx]; }
  }
  if (t == 1023) off[NN] = part[1023];
}

// ---- CSR build: scatter (src|type packed) -------------------------------
__global__ void scatter_k(const int* __restrict__ ei, const int* __restrict__ et,
                          const int* __restrict__ off, int* __restrict__ fill,
                          int* __restrict__ sorted) {
  int e = blockIdx.x * blockDim.x + threadIdx.x;
  if (e >= EE) return;
  int src = ei[e], dst = ei[EE + e], t = et[e];
  int pos = off[dst] + atomicAdd(&fill[dst], 1);
  sorted[pos] = src | (t << 20);
}

// ---- fused per-dst: FiLM agg + GAT online softmax + feats + boundaries --
__global__ __launch_bounds__(256) void dst_k(const int* __restrict__ sorted,
    const int* __restrict__ off, const float* __restrict__ Y,
    const float* __restrict__ as_, const float* __restrict__ ad_,
    const float* __restrict__ gat_b, const int* __restrict__ gb,
    float* __restrict__ feats, int* __restrict__ gstart, int* __restrict__ gend) {
  int n = blockIdx.x * 4 + (threadIdx.x >> 6);
  if (n >= NN) return;
  int h = threadIdx.x & 63;
  const float* yd = Y + (size_t)n * 832;
  float b0 = yd[384 + h], g0 = yd[448 + h];
  float b1 = yd[512 + h], g1 = yd[576 + h];
  float b2 = yd[640 + h], g2 = yd[704 + h];
  float xps = yd[768 + h];
  float adn = ad_[n];
  // self-loop seeds online-softmax state (wave-uniform m, den)
  float m = leaky02(as_[n] + adn);
  float den = 1.f;
  float S = xps;
  float f0 = 0.f, f1 = 0.f, f2 = 0.f;
  int c0 = 0, c1 = 0, c2 = 0;
  int o = off[n], oend = off[n + 1];
  for (int i = o; i < oend; i++) {
    int pk = sorted[i];                 // wave-uniform broadcast load
    int src = pk & 0xFFFFF;
    int t = pk >> 20;
    const float* ys = Y + (size_t)src * 832;
    float e = leaky02(as_[src] + adn);  // wave-uniform
    float xp = ys[768 + h];
    float xr = ys[192 + t * 64 + h];
    float mn = fmaxf(m, e);
    float sc = __expf(m - mn);
    float w  = __expf(e - mn);
    den = den * sc + w;
    S   = S * sc + w * xp;
    m = mn;
    if (t == 0)      { f0 += fmaxf(g0 * xr + b0, 0.f); c0++; }
    else if (t == 1) { f1 += fmaxf(g1 * xr + b1, 0.f); c1++; }
    else             { f2 += fmaxf(g2 * xr + b2, 0.f); c2++; }
  }
  float agg = f0 / (float)(c0 > 1 ? c0 : 1)
            + f1 / (float)(c1 > 1 ? c1 : 1)
            + f2 / (float)(c2 > 1 ? c2 : 1);
  float o1 = fmaxf(yd[h] + agg, 0.f);
  float o2 = fmaxf(S / den + gat_b[h], 0.f);
  feats[(size_t)n * 128 + h]      = o1;
  feats[(size_t)n * 128 + 64 + h] = o2;
  if (h == 0) {
    int g = gb[n];
    atomicMin(&gstart[g], n);
    atomicMax(&gend[g], n);
  }
}

// ---- parallel pooling: 8 chunks per graph, atomic max/sum ---------------
__global__ __launch_bounds__(128) void pool_k(const float* __restrict__ feats,
    const int* __restrict__ gstart, const int* __restrict__ gend,
    float* __restrict__ pmax, float* __restrict__ psum) {
  int g = blockIdx.x, chunk = blockIdx.y, f = threadIdx.x;
  int s = gstart[g], e = gend[g];
  if (s > e || s >= NN) return;
  int len = e - s + 1;
  int per = (len + 7) >> 3;
  int a = s + chunk * per;
  int bnd = a + per; if (bnd > e + 1) bnd = e + 1;
  if (a >= bnd) return;
  float mx = 0.f, sm = 0.f;          // feats >= 0 (both relu'd)
  for (int n = a; n < bnd; n++) {
    float v = feats[(size_t)n * 128 + f];
    mx = fmaxf(mx, v);
    sm += v;
  }
  atomicMaxFPos(&pmax[g * 128 + f], mx);
  atomicAdd(&psum[g * 128 + f], sm);
}

// ---- head MLP + log_softmax (fp32 out) ----------------------------------
__global__ __launch_bounds__(64) void head_k(const float* __restrict__ pmax,
    const float* __restrict__ psum, const int* __restrict__ gstart,
    const int* __restrict__ gend,
    const float* __restrict__ lin_W, const float* __restrict__ lin_b,
    const float* __restrict__ fc_W, const float* __restrict__ fc_b,
    float* __restrict__ out) {
  __shared__ float p[256];
  __shared__ float hid[64];
  __shared__ float lg[CC];
  __shared__ float lse;
  int g = blockIdx.x, t = threadIdx.x;
  int s = gstart[g], e = gend[g];
  int cnt = (s <= e && s < NN) ? (e - s + 1) : 0;
  float invc = 1.f / (float)(cnt > 1 ? cnt : 1);
  for (int i = t; i < 256; i += 64)
    p[i] = (i < 128) ? pmax[g * 128 + i] : psum[g * 128 + (i - 128)] * invc;
  __syncthreads();
  float acc = lin_b[t];
  for (int k = 0; k < 256; k++) acc += p[k] * lin_W[k * 64 + t];
  hid[t] = fmaxf(acc, 0.f);
  __syncthreads();
  if (t < CC) {
    float a = fc_b[t];
    for (int k = 0; k < 64; k++) a += hid[k] * fc_W[k * CC + t];
    lg[t] = a;
  }
  __syncthreads();
  if (t == 0) {
    float mx = lg[0];
    for (int i = 1; i < CC; i++) mx = fmaxf(mx, lg[i]);
    float sum = 0.f;
    for (int i = 0; i < CC; i++) sum += expf(lg[i] - mx);
    lse = mx + logf(sum);
  }
  __syncthreads();
  if (t < CC) out[g * CC + t] = lg[t] - lse;
}

extern "C" void kernel_launch(void* const* d_in, const int* in_sizes, int n_in,
                              void* d_out, int out_size, void* d_ws, size_t ws_size,
                              hipStream_t stream) {
  const float* x            = (const float*)d_in[0];
  const int*   edge_index   = (const int*)d_in[1];
  const int*   edge_type    = (const int*)d_in[2];
  const int*   graph_batch  = (const int*)d_in[3];
  const float* film_lin_W   = (const float*)d_in[4];
  const float* film_film_W  = (const float*)d_in[5];
  const float* film_film_b  = (const float*)d_in[6];
  const float* skip_W       = (const float*)d_in[7];
  const float* skip_film_W  = (const float*)d_in[8];
  const float* skip_film_b  = (const float*)d_in[9];
  const float* gat_W        = (const float*)d_in[10];
  const float* att_src      = (const float*)d_in[11];
  const float* att_dst      = (const float*)d_in[12];
  const float* gat_b        = (const float*)d_in[13];
  const float* lin_W        = (const float*)d_in[14];
  const float* lin_b        = (const float*)d_in[15];
  const float* fc_W         = (const float*)d_in[16];
  const float* fc_b         = (const float*)d_in[17];
  float* out                = (float*)d_out;

  float* ws = (float*)d_ws;
  const size_t N = NN, E = EE, G = GG;
  size_t oY      = 0;                       // N*832
  size_t oFeats  = N * 832;                 // N*128
  size_t oAs     = oFeats + N * 128;        // N
  size_t oAd     = oAs + N;                 // N
  size_t oW      = oAd + N;                 // 64*832
  size_t oBias   = oW + 64 * 832;           // 832
  size_t oPmax   = oBias + 832;             // G*128  } zero
  size_t oPsum   = oPmax + G * 128;         // G*128  } zero
  size_t oGend   = oPsum + G * 128;         // G      } zero
  size_t oDeg    = oGend + G;               // N      } zero
  size_t oFill   = oDeg + N;                // N      } zero
  size_t oGstart = oFill + N;               // G (0x7f)
  size_t oOff    = oGstart + G;             // N+1
  size_t oSorted = oOff + N + 1;            // E

  float* Y      = ws + oY;
  float* feats  = ws + oFeats;
  float* as_    = ws + oAs;
  float* ad_    = ws + oAd;
  float* Wcat   = ws + oW;
  float* bias   = ws + oBias;
  float* pmax   = ws + oPmax;
  float* psum   = ws + oPsum;
  int*   gend   = (int*)(ws + oGend);
  int*   deg    = (int*)(ws + oDeg);
  int*   fill   = (int*)(ws + oFill);
  int*   gstart = (int*)(ws + oGstart);
  int*   off    = (int*)(ws + oOff);
  int*   sorted = (int*)(ws + oSorted);

  size_t zeroFloats = oGstart - oPmax;   // pmax,psum,gend,deg,fill
  hipMemsetAsync(pmax, 0, zeroFloats * sizeof(float), stream);
  hipMemsetAsync(gstart, 0x7f, G * sizeof(int), stream);

  pack_w_k<<<(64 * 832 + 832 + 255) / 256, 256, 0, stream>>>(
      skip_film_W, skip_W, film_lin_W, film_film_W, gat_W,
      skip_film_b, film_film_b, Wcat, bias);
  gemm_k<<<dim3((NN + 63) / 64, 7), 256, 0, stream>>>(x, Wcat, bias, Y);
  post_k<<<(NN + 3) / 4, 256, 0, stream>>>(Y, att_src, att_dst, as_, ad_);
  count_k<<<(EE + 255) / 256, 256, 0, stream>>>(edge_index, deg);
  scan_k<<<1, 1024, 0, stream>>>(deg, off);
  scatter_k<<<(EE + 255) / 256, 256, 0, stream>>>(edge_index, edge_type,
                                                  off, fill, sorted);
  dst_k<<<(NN + 3) / 4, 256, 0, stream>>>(sorted, off, Y, as_, ad_,
                                          gat_b, graph_batch, feats, gstart, gend);
  pool_k<<<dim3(GG, 8), 128, 0, stream>>>(feats, gstart, gend, pmax, psum);
  head_k<<<GG, 64, 0, stream>>>(pmax, psum, gstart, gend,
                                lin_W, lin_b, fc_W, fc_b, out);
}

// Round 5
// 808.412 us; speedup vs baseline: 1.4907x; 1.0313x over previous
//
#include <hip/hip_runtime.h>
#include <hip/hip_bf16.h>

// Problem constants (from reference)
#define NN 50000
#define EE 800000
#define GG 64
#define RR 3
#define CC 10
// Y layout per node (832 cols): [0:128 fs | 128:192 xs | 192:384 xr(r=0..2) |
//                                384:768 fm(r, beta|gamma) | 768:832 xp]
// post_k: writes skip_out into col 0:64, builds XG bf16 [xp|xr0|xr1|xr2].
// dst_k: writes feats into cols 192:320 (xr cols are dead after XG build).

__device__ inline float leaky02(float x) { return x > 0.f ? x : 0.2f * x; }

// valid for non-negative floats only (int compare == float compare there)
__device__ inline void atomicMaxFPos(float* addr, float v) {
  atomicMax((int*)addr, __float_as_int(v));
}

// ---- pack node weights into Wcat (64 x 832) + bias vec (832) ------------
__global__ void pack_w_k(const float* __restrict__ skip_film_W,
                         const float* __restrict__ skip_W,
                         const float* __restrict__ film_lin_W,
                         const float* __restrict__ film_film_W,
                         const float* __restrict__ gat_W,
                         const float* __restrict__ skip_film_b,
                         const float* __restrict__ film_film_b,
                         float* __restrict__ Wcat, float* __restrict__ bias) {
  int idx = blockIdx.x * blockDim.x + threadIdx.x;
  if (idx >= 64 * 832 + 832) return;
  if (idx >= 64 * 832) {
    int c = idx - 64 * 832;
    float b = 0.f;
    if (c < 128) b = skip_film_b[c];
    else if (c >= 384 && c < 768) b = film_film_b[c - 384];
    bias[c] = b;
    return;
  }
  int k = idx / 832, c = idx % 832;
  float v;
  if (c < 128)      v = skip_film_W[k * 128 + c];
  else if (c < 192) v = skip_W[k * 64 + (c - 128)];
  else if (c < 384) { int cc = c - 192, r = cc >> 6, h = cc & 63;
                      v = film_lin_W[(r * 64 + k) * 64 + h]; }
  else if (c < 768) { int cc = c - 384, r = cc >> 7, j = cc & 127;
                      v = film_film_W[(r * 64 + k) * 128 + j]; }
  else              v = gat_W[k * 64 + (c - 768)];
  Wcat[idx] = v;
}

// ---- X(50000x64) @ Wcat(64x832) + bias -> Y -----------------------------
__global__ __launch_bounds__(256) void gemm_k(const float* __restrict__ X,
                                              const float* __restrict__ W,
                                              const float* __restrict__ bias,
                                              float* __restrict__ Y) {
  __shared__ __align__(16) float As[64][65];
  __shared__ __align__(16) float Bs[64][128];
  const int tid = threadIdx.x;
  const int row0 = blockIdx.x * 64;
  const int col0 = blockIdx.y * 128;

  #pragma unroll
  for (int s = 0; s < 4; s++) {
    int q = s * 256 + tid;
    int r = q >> 4;
    int c4 = (q & 15) << 2;
    int gr = row0 + r;
    float4 v = make_float4(0.f, 0.f, 0.f, 0.f);
    if (gr < NN) v = *reinterpret_cast<const float4*>(X + (size_t)gr * 64 + c4);
    As[r][c4 + 0] = v.x; As[r][c4 + 1] = v.y;
    As[r][c4 + 2] = v.z; As[r][c4 + 3] = v.w;
  }
  #pragma unroll
  for (int s = 0; s < 8; s++) {
    int q = s * 256 + tid;
    int r = q >> 5;
    int c4 = (q & 31) << 2;
    int gc = col0 + c4;
    float4 v = make_float4(0.f, 0.f, 0.f, 0.f);
    if (gc + 3 < 832) v = *reinterpret_cast<const float4*>(W + (size_t)r * 832 + gc);
    *reinterpret_cast<float4*>(&Bs[r][c4]) = v;
  }
  __syncthreads();

  const int tx = tid & 15, ty = tid >> 4;
  float acc[4][8] = {};
  #pragma unroll 8
  for (int k = 0; k < 64; k++) {
    float a0 = As[ty * 4 + 0][k], a1 = As[ty * 4 + 1][k];
    float a2 = As[ty * 4 + 2][k], a3 = As[ty * 4 + 3][k];
    const float4* bp = reinterpret_cast<const float4*>(&Bs[k][tx * 8]);
    float4 b0 = bp[0], b1 = bp[1];
    float bb[8] = {b0.x, b0.y, b0.z, b0.w, b1.x, b1.y, b1.z, b1.w};
    #pragma unroll
    for (int j = 0; j < 8; j++) {
      acc[0][j] += a0 * bb[j]; acc[1][j] += a1 * bb[j];
      acc[2][j] += a2 * bb[j]; acc[3][j] += a3 * bb[j];
    }
  }
  int gc = col0 + tx * 8;
  if (gc + 7 < 832) {
    float4 bv0 = *reinterpret_cast<const float4*>(bias + gc);
    float4 bv1 = *reinterpret_cast<const float4*>(bias + gc + 4);
    #pragma unroll
    for (int i = 0; i < 4; i++) {
      int gr = row0 + ty * 4 + i;
      if (gr >= NN) continue;
      float4 o0 = {acc[i][0] + bv0.x, acc[i][1] + bv0.y,
                   acc[i][2] + bv0.z, acc[i][3] + bv0.w};
      float4 o1 = {acc[i][4] + bv1.x, acc[i][5] + bv1.y,
                   acc[i][6] + bv1.z, acc[i][7] + bv1.w};
      *reinterpret_cast<float4*>(Y + (size_t)gr * 832 + gc) = o0;
      *reinterpret_cast<float4*>(Y + (size_t)gr * 832 + gc + 4) = o1;
    }
  }
}

// ---- per-node post: skip_out, attention scalars, XG bf16 build ----------
__global__ __launch_bounds__(256) void post_k(float* __restrict__ Y,
    const float* __restrict__ att_src, const float* __restrict__ att_dst,
    float* __restrict__ as_, float* __restrict__ ad_,
    __hip_bfloat16* __restrict__ XG) {
  int n = blockIdx.x * 4 + (threadIdx.x >> 6);
  if (n >= NN) return;
  int h = threadIdx.x & 63;
  float* y = Y + (size_t)n * 832;
  float fsb = y[h];
  float fsg = y[64 + h];
  float xs  = y[128 + h];
  float so  = fmaxf(fsg * xs + fsb, 0.f);
  float xph = y[768 + h];
  __hip_bfloat16* xg = XG + (size_t)n * 256;
  xg[h]       = __float2bfloat16(xph);
  xg[64 + h]  = __float2bfloat16(y[192 + h]);
  xg[128 + h] = __float2bfloat16(y[256 + h]);
  xg[192 + h] = __float2bfloat16(y[320 + h]);
  float pa = xph * att_src[h], pd = xph * att_dst[h];
  #pragma unroll
  for (int off = 32; off > 0; off >>= 1) {
    pa += __shfl_xor(pa, off);
    pd += __shfl_xor(pd, off);
  }
  y[h] = so;
  if (h == 0) { as_[n] = pa; ad_[n] = pd; }
}

// ---- CSR build: count ----------------------------------------------------
__global__ void count_k(const int* __restrict__ ei, int* __restrict__ deg) {
  int e = blockIdx.x * blockDim.x + threadIdx.x;
  if (e >= EE) return;
  atomicAdd(&deg[ei[EE + e]], 1);
}

// ---- 3-phase parallel exclusive scan ------------------------------------
#define NT 196   // ceil(50000/256)
__global__ __launch_bounds__(256) void scanA_k(const int* __restrict__ deg,
    int* __restrict__ off, int* __restrict__ tsum) {
  __shared__ int s[256];
  int t = threadIdx.x, idx = blockIdx.x * 256 + t;
  int v = (idx < NN) ? deg[idx] : 0;
  s[t] = v;
  __syncthreads();
  for (int ofs = 1; ofs < 256; ofs <<= 1) {
    int u = (t >= ofs) ? s[t - ofs] : 0;
    __syncthreads();
    s[t] += u;
    __syncthreads();
  }
  if (idx < NN) off[idx] = s[t] - v;
  if (t == 255) tsum[blockIdx.x] = s[255];
}

__global__ __launch_bounds__(256) void scanB_k(const int* __restrict__ tsum,
    int* __restrict__ tbase, int* __restrict__ off) {
  __shared__ int s[256];
  int t = threadIdx.x;
  int v = (t < NT) ? tsum[t] : 0;
  s[t] = v;
  __syncthreads();
  for (int ofs = 1; ofs < 256; ofs <<= 1) {
    int u = (t >= ofs) ? s[t - ofs] : 0;
    __syncthreads();
    s[t] += u;
    __syncthreads();
  }
  if (t < NT) tbase[t] = s[t] - v;
  if (t == 255) off[NN] = s[255];
}

__global__ __launch_bounds__(256) void scanC_k(int* __restrict__ off,
    const int* __restrict__ tbase) {
  int idx = blockIdx.x * 256 + threadIdx.x;
  if (idx < NN) off[idx] += tbase[blockIdx.x];
}

// ---- CSR build: scatter (src|type packed) -------------------------------
__global__ void scatter_k(const int* __restrict__ ei, const int* __restrict__ et,
                          const int* __restrict__ off, int* __restrict__ fill,
                          int* __restrict__ sorted) {
  int e = blockIdx.x * blockDim.x + threadIdx.x;
  if (e >= EE) return;
  int src = ei[e], dst = ei[EE + e], t = et[e];
  int pos = off[dst] + atomicAdd(&fill[dst], 1);
  sorted[pos] = src | (t << 20);
}

// ---- fused per-dst: lane-parallel softmax phase + unrolled gather phase --
// FILM update: t is wave-uniform (broadcast), so branches are uniform.
#define FILM(P, XR) {                                            \
    int t_ = (P) >> 20;                                          \
    float gt_ = t_ == 0 ? g0 : (t_ == 1 ? g1 : g2);              \
    float bt_ = t_ == 0 ? b0 : (t_ == 1 ? b1 : b2);              \
    float msg_ = fmaxf(gt_ * (XR) + bt_, 0.f);                   \
    if (t_ == 0)      { f0 += msg_; c0++; }                      \
    else if (t_ == 1) { f1 += msg_; c1++; }                      \
    else              { f2 += msg_; c2++; }                      \
  }

__global__ __launch_bounds__(256) void dst_k(const int* __restrict__ sorted,
    const int* __restrict__ off, float* __restrict__ Y,
    const __hip_bfloat16* __restrict__ XG,
    const float* __restrict__ as_, const float* __restrict__ ad_,
    const float* __restrict__ gat_b, const int* __restrict__ gb,
    int* __restrict__ gstart, int* __restrict__ gend) {
  int n = blockIdx.x * 4 + (threadIdx.x >> 6);
  if (n >= NN) return;
  int h = threadIdx.x & 63;
  float* yd = Y + (size_t)n * 832;
  float b0 = yd[384 + h], g0 = yd[448 + h];
  float b1 = yd[512 + h], g1 = yd[576 + h];
  float b2 = yd[640 + h], g2 = yd[704 + h];
  float adn = ad_[n];
  float m = leaky02(as_[n] + adn);     // self-loop seeds softmax state
  float den = 1.f;
  float S = yd[768 + h];               // self xp (fp32)
  float f0 = 0.f, f1 = 0.f, f2 = 0.f;
  int c0 = 0, c1 = 0, c2 = 0;
  int o = off[n], deg = off[n + 1] - o;

  for (int base = 0; base < deg; base += 64) {
    int cn = deg - base; if (cn > 64) cn = 64;
    int pk = 0; float e = -1e30f;
    if (h < cn) {
      pk = sorted[o + base + h];              // coalesced
      int s0 = pk & 0xFFFFF;
      if (s0 >= NN) s0 = NN - 1;              // defensive clamp
      e = leaky02(as_[s0] + adn);             // lane-parallel 4B gather
    }
    float cm = e;
    #pragma unroll
    for (int ofs = 32; ofs > 0; ofs >>= 1) cm = fmaxf(cm, __shfl_xor(cm, ofs));
    float mn = fmaxf(m, cm);
    float w = __expf(e - mn);                 // ~0 for inactive lanes
    float ds = w;
    #pragma unroll
    for (int ofs = 32; ofs > 0; ofs >>= 1) ds += __shfl_xor(ds, ofs);
    float sc = __expf(m - mn);
    den = den * sc + ds;
    S *= sc;
    m = mn;
    // feature phase: broadcast edge -> independent gathers, unrolled x4
    int i = 0;
    for (; i + 4 <= cn; i += 4) {
      int p0 = __shfl(pk, i),     p1 = __shfl(pk, i + 1);
      int p2 = __shfl(pk, i + 2), p3 = __shfl(pk, i + 3);
      float w0 = __shfl(w, i),     w1 = __shfl(w, i + 1);
      float w2 = __shfl(w, i + 2), w3 = __shfl(w, i + 3);
      int s0 = p0 & 0xFFFFF; if (s0 >= NN) s0 = NN - 1;
      int s1 = p1 & 0xFFFFF; if (s1 >= NN) s1 = NN - 1;
      int s2 = p2 & 0xFFFFF; if (s2 >= NN) s2 = NN - 1;
      int s3 = p3 & 0xFFFFF; if (s3 >= NN) s3 = NN - 1;
      const __hip_bfloat16* x0 = XG + (size_t)s0 * 256;
      const __hip_bfloat16* x1 = XG + (size_t)s1 * 256;
      const __hip_bfloat16* x2 = XG + (size_t)s2 * 256;
      const __hip_bfloat16* x3 = XG + (size_t)s3 * 256;
      float xp0 = __bfloat162float(x0[h]), xp1 = __bfloat162float(x1[h]);
      float xp2 = __bfloat162float(x2[h]), xp3 = __bfloat162float(x3[h]);
      float xr0 = __bfloat162float(x0[64 + ((p0 >> 20) << 6) + h]);
      float xr1 = __bfloat162float(x1[64 + ((p1 >> 20) << 6) + h]);
      float xr2 = __bfloat162float(x2[64 + ((p2 >> 20) << 6) + h]);
      float xr3 = __bfloat162float(x3[64 + ((p3 >> 20) << 6) + h]);
      S += w0 * xp0 + w1 * xp1 + w2 * xp2 + w3 * xp3;
      FILM(p0, xr0); FILM(p1, xr1); FILM(p2, xr2); FILM(p3, xr3);
    }
    for (; i < cn; i++) {
      int p = __shfl(pk, i);
      float wi = __shfl(w, i);
      int s0 = p & 0xFFFFF; if (s0 >= NN) s0 = NN - 1;
      const __hip_bfloat16* xx = XG + (size_t)s0 * 256;
      float xp = __bfloat162float(xx[h]);
      float xr = __bfloat162float(xx[64 + ((p >> 20) << 6) + h]);
      S += wi * xp;
      FILM(p, xr);
    }
  }
  float agg = f0 / (float)(c0 > 1 ? c0 : 1)
            + f1 / (float)(c1 > 1 ? c1 : 1)
            + f2 / (float)(c2 > 1 ? c2 : 1);
  float o1 = fmaxf(yd[h] + agg, 0.f);
  float o2 = fmaxf(S / den + gat_b[h], 0.f);
  yd[192 + h] = o1;                 // feats stored in freed xr cols
  yd[256 + h] = o2;
  if (h == 0) {
    int g = gb[n];
    atomicMin(&gstart[g], n);
    atomicMax(&gend[g], n);
  }
}

// ---- parallel pooling: 8 chunks per graph, atomic max/sum ---------------
__global__ __launch_bounds__(128) void pool_k(const float* __restrict__ Y,
    const int* __restrict__ gstart, const int* __restrict__ gend,
    float* __restrict__ pmax, float* __restrict__ psum) {
  int g = blockIdx.x, chunk = blockIdx.y, f = threadIdx.x;
  int s = gstart[g], e = gend[g];
  if (s > e || s >= NN || s < 0) return;
  if (e >= NN) e = NN - 1;
  int len = e - s + 1;
  int per = (len + 7) >> 3;
  int a = s + chunk * per;
  int bnd = a + per; if (bnd > e + 1) bnd = e + 1;
  if (a >= bnd) return;
  float mx = 0.f, sm = 0.f;          // feats >= 0 (both relu'd)
  for (int n = a; n < bnd; n++) {
    float v = Y[(size_t)n * 832 + 192 + f];
    mx = fmaxf(mx, v);
    sm += v;
  }
  atomicMaxFPos(&pmax[g * 128 + f], mx);
  atomicAdd(&psum[g * 128 + f], sm);
}

// ---- head MLP + log_softmax (fp32 out) ----------------------------------
__global__ __launch_bounds__(64) void head_k(const float* __restrict__ pmax,
    const float* __restrict__ psum, const int* __restrict__ gstart,
    const int* __restrict__ gend,
    const float* __restrict__ lin_W, const float* __restrict__ lin_b,
    const float* __restrict__ fc_W, const float* __restrict__ fc_b,
    float* __restrict__ out) {
  __shared__ float p[256];
  __shared__ float hid[64];
  __shared__ float lg[CC];
  __shared__ float lse;
  int g = blockIdx.x, t = threadIdx.x;
  int s = gstart[g], e = gend[g];
  int cnt = (s <= e && s < NN && s >= 0) ? (e - s + 1) : 0;
  float invc = 1.f / (float)(cnt > 1 ? cnt : 1);
  for (int i = t; i < 256; i += 64)
    p[i] = (i < 128) ? pmax[g * 128 + i] : psum[g * 128 + (i - 128)] * invc;
  __syncthreads();
  float acc = lin_b[t];
  for (int k = 0; k < 256; k++) acc += p[k] * lin_W[k * 64 + t];
  hid[t] = fmaxf(acc, 0.f);
  __syncthreads();
  if (t < CC) {
    float a = fc_b[t];
    for (int k = 0; k < 64; k++) a += hid[k] * fc_W[k * CC + t];
    lg[t] = a;
  }
  __syncthreads();
  if (t == 0) {
    float mx = lg[0];
    for (int i = 1; i < CC; i++) mx = fmaxf(mx, lg[i]);
    float sum = 0.f;
    for (int i = 0; i < CC; i++) sum += expf(lg[i] - mx);
    lse = mx + logf(sum);
  }
  __syncthreads();
  if (t < CC) out[g * CC + t] = lg[t] - lse;
}

extern "C" void kernel_launch(void* const* d_in, const int* in_sizes, int n_in,
                              void* d_out, int out_size, void* d_ws, size_t ws_size,
                              hipStream_t stream) {
  const float* x            = (const float*)d_in[0];
  const int*   edge_index   = (const int*)d_in[1];
  const int*   edge_type    = (const int*)d_in[2];
  const int*   graph_batch  = (const int*)d_in[3];
  const float* film_lin_W   = (const float*)d_in[4];
  const float* film_film_W  = (const float*)d_in[5];
  const float* film_film_b  = (const float*)d_in[6];
  const float* skip_W       = (const float*)d_in[7];
  const float* skip_film_W  = (const float*)d_in[8];
  const float* skip_film_b  = (const float*)d_in[9];
  const float* gat_W        = (const float*)d_in[10];
  const float* att_src      = (const float*)d_in[11];
  const float* att_dst      = (const float*)d_in[12];
  const float* gat_b        = (const float*)d_in[13];
  const float* lin_W        = (const float*)d_in[14];
  const float* lin_b        = (const float*)d_in[15];
  const float* fc_W         = (const float*)d_in[16];
  const float* fc_b         = (const float*)d_in[17];
  float* out                = (float*)d_out;

  float* ws = (float*)d_ws;
  const size_t N = NN, E = EE, G = GG;
  size_t oY      = 0;                       // N*832
  size_t oXG     = N * 832;                 // N*128 float slots (N*256 bf16)
  size_t oAs     = oXG + N * 128;           // N
  size_t oAd     = oAs + N;                 // N
  size_t oW      = oAd + N;                 // 64*832
  size_t oBias   = oW + 64 * 832;           // 832
  size_t oPmax   = oBias + 832;             // G*128 } zero region
  size_t oPsum   = oPmax + G * 128;         // G*128 }
  size_t oGend   = oPsum + G * 128;         // G     }
  size_t oDeg    = oGend + G;               // N     }
  size_t oFill   = oDeg + N;                // N     }
  size_t oGstart = oFill + N;               // G (0x7f)
  size_t oOff    = oGstart + G;             // N+1
  size_t oTsum   = oOff + N + 1;            // 256
  size_t oTbase  = oTsum + 256;             // 256
  size_t oSorted = oTbase + 256;            // E

  float* Y      = ws + oY;
  __hip_bfloat16* XG = (__hip_bfloat16*)(ws + oXG);
  float* as_    = ws + oAs;
  float* ad_    = ws + oAd;
  float* Wcat   = ws + oW;
  float* bias   = ws + oBias;
  float* pmax   = ws + oPmax;
  float* psum   = ws + oPsum;
  int*   gend   = (int*)(ws + oGend);
  int*   deg    = (int*)(ws + oDeg);
  int*   fill   = (int*)(ws + oFill);
  int*   gstart = (int*)(ws + oGstart);
  int*   off    = (int*)(ws + oOff);
  int*   tsum   = (int*)(ws + oTsum);
  int*   tbase  = (int*)(ws + oTbase);
  int*   sorted = (int*)(ws + oSorted);

  size_t zeroFloats = oGstart - oPmax;   // pmax,psum,gend,deg,fill
  hipMemsetAsync(pmax, 0, zeroFloats * sizeof(float), stream);
  hipMemsetAsync(gstart, 0x7f, G * sizeof(int), stream);

  pack_w_k<<<(64 * 832 + 832 + 255) / 256, 256, 0, stream>>>(
      skip_film_W, skip_W, film_lin_W, film_film_W, gat_W,
      skip_film_b, film_film_b, Wcat, bias);
  gemm_k<<<dim3((NN + 63) / 64, 7), 256, 0, stream>>>(x, Wcat, bias, Y);
  post_k<<<(NN + 3) / 4, 256, 0, stream>>>(Y, att_src, att_dst, as_, ad_, XG);
  count_k<<<(EE + 255) / 256, 256, 0, stream>>>(edge_index, deg);
  scanA_k<<<NT, 256, 0, stream>>>(deg, off, tsum);
  scanB_k<<<1, 256, 0, stream>>>(tsum, tbase, off);
  scanC_k<<<NT, 256, 0, stream>>>(off, tbase);
  scatter_k<<<(EE + 255) / 256, 256, 0, stream>>>(edge_index, edge_type,
                                                  off, fill, sorted);
  dst_k<<<(NN + 3) / 4, 256, 0, stream>>>(sorted, off, Y, XG, as_, ad_,
                                          gat_b, graph_batch, gstart, gend);
  pool_k<<<dim3(GG, 8), 128, 0, stream>>>(Y, gstart, gend, pmax, psum);
  head_k<<<GG, 64, 0, stream>>>(pmax, psum, gstart, gend,
                                lin_W, lin_b, fc_W, fc_b, out);
}

// Round 6
// 733.141 us; speedup vs baseline: 1.6437x; 1.1027x over previous
//
#include <hip/hip_runtime.h>
#include <hip/hip_bf16.h>

// Problem constants (from reference)
#define NN 50000
#define EE 800000
#define GG 64
#define RR 3
#define CC 10
// Y layout per node (832 cols): [0:128 fs | 128:192 xs | 192:384 xr(r=0..2) |
//                                384:768 fm(r, beta|gamma) | 768:832 xp]
// post_k: writes skip_out into col 0:64, builds XG bf16 [xp|xr0|xr1|xr2].
// dst_k: writes feats into cols 192:320 (xr cols are dead after XG build).

__device__ inline float leaky02(float x) { return x > 0.f ? x : 0.2f * x; }

// valid for non-negative floats only (int compare == float compare there)
__device__ inline void atomicMaxFPos(float* addr, float v) {
  atomicMax((int*)addr, __float_as_int(v));
}

// ---- pack node weights into Wcat (64 x 832) + bias vec (832) ------------
__global__ void pack_w_k(const float* __restrict__ skip_film_W,
                         const float* __restrict__ skip_W,
                         const float* __restrict__ film_lin_W,
                         const float* __restrict__ film_film_W,
                         const float* __restrict__ gat_W,
                         const float* __restrict__ skip_film_b,
                         const float* __restrict__ film_film_b,
                         float* __restrict__ Wcat, float* __restrict__ bias) {
  int idx = blockIdx.x * blockDim.x + threadIdx.x;
  if (idx >= 64 * 832 + 832) return;
  if (idx >= 64 * 832) {
    int c = idx - 64 * 832;
    float b = 0.f;
    if (c < 128) b = skip_film_b[c];
    else if (c >= 384 && c < 768) b = film_film_b[c - 384];
    bias[c] = b;
    return;
  }
  int k = idx / 832, c = idx % 832;
  float v;
  if (c < 128)      v = skip_film_W[k * 128 + c];
  else if (c < 192) v = skip_W[k * 64 + (c - 128)];
  else if (c < 384) { int cc = c - 192, r = cc >> 6, h = cc & 63;
                      v = film_lin_W[(r * 64 + k) * 64 + h]; }
  else if (c < 768) { int cc = c - 384, r = cc >> 7, j = cc & 127;
                      v = film_film_W[(r * 64 + k) * 128 + j]; }
  else              v = gat_W[k * 64 + (c - 768)];
  Wcat[idx] = v;
}

// ---- X(50000x64) @ Wcat(64x832) + bias -> Y -----------------------------
__global__ __launch_bounds__(256) void gemm_k(const float* __restrict__ X,
                                              const float* __restrict__ W,
                                              const float* __restrict__ bias,
                                              float* __restrict__ Y) {
  __shared__ __align__(16) float As[64][65];
  __shared__ __align__(16) float Bs[64][128];
  const int tid = threadIdx.x;
  const int row0 = blockIdx.x * 64;
  const int col0 = blockIdx.y * 128;

  #pragma unroll
  for (int s = 0; s < 4; s++) {
    int q = s * 256 + tid;
    int r = q >> 4;
    int c4 = (q & 15) << 2;
    int gr = row0 + r;
    float4 v = make_float4(0.f, 0.f, 0.f, 0.f);
    if (gr < NN) v = *reinterpret_cast<const float4*>(X + (size_t)gr * 64 + c4);
    As[r][c4 + 0] = v.x; As[r][c4 + 1] = v.y;
    As[r][c4 + 2] = v.z; As[r][c4 + 3] = v.w;
  }
  #pragma unroll
  for (int s = 0; s < 8; s++) {
    int q = s * 256 + tid;
    int r = q >> 5;
    int c4 = (q & 31) << 2;
    int gc = col0 + c4;
    float4 v = make_float4(0.f, 0.f, 0.f, 0.f);
    if (gc + 3 < 832) v = *reinterpret_cast<const float4*>(W + (size_t)r * 832 + gc);
    *reinterpret_cast<float4*>(&Bs[r][c4]) = v;
  }
  __syncthreads();

  const int tx = tid & 15, ty = tid >> 4;
  float acc[4][8] = {};
  #pragma unroll 8
  for (int k = 0; k < 64; k++) {
    float a0 = As[ty * 4 + 0][k], a1 = As[ty * 4 + 1][k];
    float a2 = As[ty * 4 + 2][k], a3 = As[ty * 4 + 3][k];
    const float4* bp = reinterpret_cast<const float4*>(&Bs[k][tx * 8]);
    float4 b0 = bp[0], b1 = bp[1];
    float bb[8] = {b0.x, b0.y, b0.z, b0.w, b1.x, b1.y, b1.z, b1.w};
    #pragma unroll
    for (int j = 0; j < 8; j++) {
      acc[0][j] += a0 * bb[j]; acc[1][j] += a1 * bb[j];
      acc[2][j] += a2 * bb[j]; acc[3][j] += a3 * bb[j];
    }
  }
  int gc = col0 + tx * 8;
  if (gc + 7 < 832) {
    float4 bv0 = *reinterpret_cast<const float4*>(bias + gc);
    float4 bv1 = *reinterpret_cast<const float4*>(bias + gc + 4);
    #pragma unroll
    for (int i = 0; i < 4; i++) {
      int gr = row0 + ty * 4 + i;
      if (gr >= NN) continue;
      float4 o0 = {acc[i][0] + bv0.x, acc[i][1] + bv0.y,
                   acc[i][2] + bv0.z, acc[i][3] + bv0.w};
      float4 o1 = {acc[i][4] + bv1.x, acc[i][5] + bv1.y,
                   acc[i][6] + bv1.z, acc[i][7] + bv1.w};
      *reinterpret_cast<float4*>(Y + (size_t)gr * 832 + gc) = o0;
      *reinterpret_cast<float4*>(Y + (size_t)gr * 832 + gc + 4) = o1;
    }
  }
}

// ---- per-node post: skip_out, attention scalars, XG bf16 build ----------
__global__ __launch_bounds__(256) void post_k(float* __restrict__ Y,
    const float* __restrict__ att_src, const float* __restrict__ att_dst,
    float* __restrict__ as_, float* __restrict__ ad_,
    __hip_bfloat16* __restrict__ XG) {
  int n = blockIdx.x * 4 + (threadIdx.x >> 6);
  if (n >= NN) return;
  int h = threadIdx.x & 63;
  float* y = Y + (size_t)n * 832;
  float fsb = y[h];
  float fsg = y[64 + h];
  float xs  = y[128 + h];
  float so  = fmaxf(fsg * xs + fsb, 0.f);
  float xph = y[768 + h];
  __hip_bfloat16* xg = XG + (size_t)n * 256;
  xg[h]       = __float2bfloat16(xph);
  xg[64 + h]  = __float2bfloat16(y[192 + h]);
  xg[128 + h] = __float2bfloat16(y[256 + h]);
  xg[192 + h] = __float2bfloat16(y[320 + h]);
  float pa = xph * att_src[h], pd = xph * att_dst[h];
  #pragma unroll
  for (int off = 32; off > 0; off >>= 1) {
    pa += __shfl_xor(pa, off);
    pd += __shfl_xor(pd, off);
  }
  y[h] = so;
  if (h == 0) { as_[n] = pa; ad_[n] = pd; }
}

// ---- CSR build: count ----------------------------------------------------
__global__ void count_k(const int* __restrict__ ei, int* __restrict__ deg) {
  int e = blockIdx.x * blockDim.x + threadIdx.x;
  if (e >= EE) return;
  atomicAdd(&deg[ei[EE + e]], 1);
}

// ---- 3-phase parallel exclusive scan ------------------------------------
#define NT 196   // ceil(50000/256)
__global__ __launch_bounds__(256) void scanA_k(const int* __restrict__ deg,
    int* __restrict__ off, int* __restrict__ tsum) {
  __shared__ int s[256];
  int t = threadIdx.x, idx = blockIdx.x * 256 + t;
  int v = (idx < NN) ? deg[idx] : 0;
  s[t] = v;
  __syncthreads();
  for (int ofs = 1; ofs < 256; ofs <<= 1) {
    int u = (t >= ofs) ? s[t - ofs] : 0;
    __syncthreads();
    s[t] += u;
    __syncthreads();
  }
  if (idx < NN) off[idx] = s[t] - v;
  if (t == 255) tsum[blockIdx.x] = s[255];
}

__global__ __launch_bounds__(256) void scanB_k(const int* __restrict__ tsum,
    int* __restrict__ tbase, int* __restrict__ off) {
  __shared__ int s[256];
  int t = threadIdx.x;
  int v = (t < NT) ? tsum[t] : 0;
  s[t] = v;
  __syncthreads();
  for (int ofs = 1; ofs < 256; ofs <<= 1) {
    int u = (t >= ofs) ? s[t - ofs] : 0;
    __syncthreads();
    s[t] += u;
    __syncthreads();
  }
  if (t < NT) tbase[t] = s[t] - v;
  if (t == 255) off[NN] = s[255];
}

__global__ __launch_bounds__(256) void scanC_k(int* __restrict__ off,
    const int* __restrict__ tbase) {
  int idx = blockIdx.x * 256 + threadIdx.x;
  if (idx < NN) off[idx] += tbase[blockIdx.x];
}

// ---- CSR build: scatter (src|type packed) -------------------------------
__global__ void scatter_k(const int* __restrict__ ei, const int* __restrict__ et,
                          const int* __restrict__ off, int* __restrict__ fill,
                          int* __restrict__ sorted) {
  int e = blockIdx.x * blockDim.x + threadIdx.x;
  if (e >= EE) return;
  int src = ei[e], dst = ei[EE + e], t = et[e];
  int pos = off[dst] + atomicAdd(&fill[dst], 1);
  sorted[pos] = src | (t << 20);
}

// ---- fused per-dst with cooperative block-level gather into LDS ----------
// Block = 4 nodes (one per wave). Per round: 16 edges/node. 256 threads
// cooperatively fetch the 128 needed XG rows (128B each) as 8-lane x 16B
// segments -> ~1024 outstanding requests per block (MLP fix).
#define RPN 16    // edges per node per round
#define CAPE 256  // max edges per block window (4 x Poisson(16); P(>256)~0)

__global__ __launch_bounds__(256) void dst_k(const int* __restrict__ sorted,
    const int* __restrict__ off, float* __restrict__ Y,
    const __hip_bfloat16* __restrict__ XG,
    const float* __restrict__ as_, const float* __restrict__ ad_,
    const float* __restrict__ gat_b, const int* __restrict__ gb,
    int* __restrict__ gstart, int* __restrict__ gend) {
  __shared__ int   s_pk[CAPE];
  __shared__ float s_as[CAPE];
  __shared__ __align__(16) __hip_bfloat16 s_rows[64][2][64];  // 16 KB
  __shared__ int s_b[4], s_deg[4];

  int tid = threadIdx.x;
  int wid = tid >> 6, h = tid & 63;
  int n0 = blockIdx.x * 4;
  int n = n0 + wid;                      // always < NN (50000 = 12500*4)

  int o0 = off[n0];
  int T = off[n0 + 4] - o0; if (T > CAPE) T = CAPE;

  // prefetch packed edges + as_[src] for the whole block window (coalesced)
  if (tid < T) {
    int pk = sorted[o0 + tid];
    s_pk[tid] = pk;
    int s = pk & 0xFFFFF; if (s >= NN) s = NN - 1;
    s_as[tid] = as_[s];
  }
  if (h == 0) {
    int on = off[n], on1 = off[n + 1];
    int b = on - o0, d = on1 - on;
    if (b > CAPE) b = CAPE;
    if (b + d > CAPE) d = CAPE - b;
    s_b[wid] = b; s_deg[wid] = d;
  }
  __syncthreads();

  int myb = s_b[wid], mydeg = s_deg[wid];
  int dmax = max(max(s_deg[0], s_deg[1]), max(s_deg[2], s_deg[3]));
  int rounds = (dmax + RPN - 1) / RPN;

  float* yd = Y + (size_t)n * 832;
  float b0 = yd[384 + h], g0 = yd[448 + h];
  float b1 = yd[512 + h], g1 = yd[576 + h];
  float b2 = yd[640 + h], g2 = yd[704 + h];
  float adn = ad_[n];
  float m = leaky02(as_[n] + adn);     // self-loop seeds softmax state
  float den = 1.f;
  float S = yd[768 + h];               // self xp (fp32)
  float f0 = 0.f, f1 = 0.f, f2 = 0.f;
  int c0 = 0, c1 = 0, c2 = 0;

  const int grp = tid >> 3, lane8 = tid & 7;   // 32 groups of 8 lanes

  for (int r = 0; r < rounds; r++) {
    int e0 = r * RPN;
    // ---- cooperative gather: 128 rows (64 slots x {xp, xr_t}) ----
    #pragma unroll
    for (int k = 0; k < 4; k++) {
      int ri = grp + 32 * k;            // 0..127
      int slot = ri & 63;               // node wid_s = slot>>4, j = slot&15
      int part = ri >> 6;               // 0 = xp, 1 = xr_t
      int wd = slot >> 4, j = slot & 15;
      int jj = e0 + j;
      if (jj < s_deg[wd]) {
        int be = (s_b[wd] + jj) & (CAPE - 1);
        int pk = s_pk[be];
        int src = pk & 0xFFFFF; if (src >= NN) src = NN - 1;
        int t = pk >> 20;
        const __hip_bfloat16* row = XG + (size_t)src * 256
                                  + (part ? (64 + (t << 6)) : 0);
        uint4 v = *reinterpret_cast<const uint4*>(row + lane8 * 8);
        *reinterpret_cast<uint4*>(&s_rows[slot][part][lane8 * 8]) = v;
      }
    }
    __syncthreads();
    // ---- consume: wave `wid` processes its node's <=16 edges from LDS ----
    int cn = mydeg - e0; if (cn > RPN) cn = RPN;
    if (cn > 0) {
      float e = -1e30f;
      if (h < cn) e = leaky02(s_as[(myb + e0 + h) & (CAPE - 1)] + adn);
      float cm = e;
      #pragma unroll
      for (int ofs = 32; ofs > 0; ofs >>= 1) cm = fmaxf(cm, __shfl_xor(cm, ofs));
      float mn = fmaxf(m, cm);
      float w = (h < cn) ? __expf(e - mn) : 0.f;
      float ds = w;
      #pragma unroll
      for (int ofs = 32; ofs > 0; ofs >>= 1) ds += __shfl_xor(ds, ofs);
      float sc = __expf(m - mn);
      den = den * sc + ds;
      S *= sc;
      m = mn;
      for (int j = 0; j < cn; j++) {
        float wj = __shfl(w, j);
        int pkj = s_pk[(myb + e0 + j) & (CAPE - 1)];  // uniform -> broadcast
        int tj = pkj >> 20;
        int slot = wid * RPN + j;
        float xp = __bfloat162float(s_rows[slot][0][h]);
        float xr = __bfloat162float(s_rows[slot][1][h]);
        S += wj * xp;
        float gt = tj == 0 ? g0 : (tj == 1 ? g1 : g2);
        float bt = tj == 0 ? b0 : (tj == 1 ? b1 : b2);
        float msg = fmaxf(gt * xr + bt, 0.f);
        if (tj == 0)      { f0 += msg; c0++; }
        else if (tj == 1) { f1 += msg; c1++; }
        else              { f2 += msg; c2++; }
      }
    }
    __syncthreads();
  }

  float agg = f0 / (float)(c0 > 1 ? c0 : 1)
            + f1 / (float)(c1 > 1 ? c1 : 1)
            + f2 / (float)(c2 > 1 ? c2 : 1);
  float o1 = fmaxf(yd[h] + agg, 0.f);
  float o2 = fmaxf(S / den + gat_b[h], 0.f);
  yd[192 + h] = o1;                 // feats stored in freed xr cols
  yd[256 + h] = o2;
  if (h == 0) {
    int g = gb[n];
    atomicMin(&gstart[g], n);
    atomicMax(&gend[g], n);
  }
}

// ---- parallel pooling: 8 chunks per graph, atomic max/sum ---------------
__global__ __launch_bounds__(128) void pool_k(const float* __restrict__ Y,
    const int* __restrict__ gstart, const int* __restrict__ gend,
    float* __restrict__ pmax, float* __restrict__ psum) {
  int g = blockIdx.x, chunk = blockIdx.y, f = threadIdx.x;
  int s = gstart[g], e = gend[g];
  if (s > e || s >= NN || s < 0) return;
  if (e >= NN) e = NN - 1;
  int len = e - s + 1;
  int per = (len + 7) >> 3;
  int a = s + chunk * per;
  int bnd = a + per; if (bnd > e + 1) bnd = e + 1;
  if (a >= bnd) return;
  float mx = 0.f, sm = 0.f;          // feats >= 0 (both relu'd)
  for (int n = a; n < bnd; n++) {
    float v = Y[(size_t)n * 832 + 192 + f];
    mx = fmaxf(mx, v);
    sm += v;
  }
  atomicMaxFPos(&pmax[g * 128 + f], mx);
  atomicAdd(&psum[g * 128 + f], sm);
}

// ---- head MLP + log_softmax (fp32 out) ----------------------------------
__global__ __launch_bounds__(64) void head_k(const float* __restrict__ pmax,
    const float* __restrict__ psum, const int* __restrict__ gstart,
    const int* __restrict__ gend,
    const float* __restrict__ lin_W, const float* __restrict__ lin_b,
    const float* __restrict__ fc_W, const float* __restrict__ fc_b,
    float* __restrict__ out) {
  __shared__ float p[256];
  __shared__ float hid[64];
  __shared__ float lg[CC];
  __shared__ float lse;
  int g = blockIdx.x, t = threadIdx.x;
  int s = gstart[g], e = gend[g];
  int cnt = (s <= e && s < NN && s >= 0) ? (e - s + 1) : 0;
  float invc = 1.f / (float)(cnt > 1 ? cnt : 1);
  for (int i = t; i < 256; i += 64)
    p[i] = (i < 128) ? pmax[g * 128 + i] : psum[g * 128 + (i - 128)] * invc;
  __syncthreads();
  float acc = lin_b[t];
  for (int k = 0; k < 256; k++) acc += p[k] * lin_W[k * 64 + t];
  hid[t] = fmaxf(acc, 0.f);
  __syncthreads();
  if (t < CC) {
    float a = fc_b[t];
    for (int k = 0; k < 64; k++) a += hid[k] * fc_W[k * CC + t];
    lg[t] = a;
  }
  __syncthreads();
  if (t == 0) {
    float mx = lg[0];
    for (int i = 1; i < CC; i++) mx = fmaxf(mx, lg[i]);
    float sum = 0.f;
    for (int i = 0; i < CC; i++) sum += expf(lg[i] - mx);
    lse = mx + logf(sum);
  }
  __syncthreads();
  if (t < CC) out[g * CC + t] = lg[t] - lse;
}

extern "C" void kernel_launch(void* const* d_in, const int* in_sizes, int n_in,
                              void* d_out, int out_size, void* d_ws, size_t ws_size,
                              hipStream_t stream) {
  const float* x            = (const float*)d_in[0];
  const int*   edge_index   = (const int*)d_in[1];
  const int*   edge_type    = (const int*)d_in[2];
  const int*   graph_batch  = (const int*)d_in[3];
  const float* film_lin_W   = (const float*)d_in[4];
  const float* film_film_W  = (const float*)d_in[5];
  const float* film_film_b  = (const float*)d_in[6];
  const float* skip_W       = (const float*)d_in[7];
  const float* skip_film_W  = (const float*)d_in[8];
  const float* skip_film_b  = (const float*)d_in[9];
  const float* gat_W        = (const float*)d_in[10];
  const float* att_src      = (const float*)d_in[11];
  const float* att_dst      = (const float*)d_in[12];
  const float* gat_b        = (const float*)d_in[13];
  const float* lin_W        = (const float*)d_in[14];
  const float* lin_b        = (const float*)d_in[15];
  const float* fc_W         = (const float*)d_in[16];
  const float* fc_b         = (const float*)d_in[17];
  float* out                = (float*)d_out;

  float* ws = (float*)d_ws;
  const size_t N = NN, E = EE, G = GG;
  size_t oY      = 0;                       // N*832
  size_t oXG     = N * 832;                 // N*128 float slots (N*256 bf16)
  size_t oAs     = oXG + N * 128;           // N
  size_t oAd     = oAs + N;                 // N
  size_t oW      = oAd + N;                 // 64*832
  size_t oBias   = oW + 64 * 832;           // 832
  size_t oPmax   = oBias + 832;             // G*128 } zero region
  size_t oPsum   = oPmax + G * 128;         // G*128 }
  size_t oGend   = oPsum + G * 128;         // G     }
  size_t oDeg    = oGend + G;               // N     }
  size_t oFill   = oDeg + N;                // N     }
  size_t oGstart = oFill + N;               // G (0x7f)
  size_t oOff    = oGstart + G;             // N+1
  size_t oTsum   = oOff + N + 1;            // 256
  size_t oTbase  = oTsum + 256;             // 256
  size_t oSorted = oTbase + 256;            // E

  float* Y      = ws + oY;
  __hip_bfloat16* XG = (__hip_bfloat16*)(ws + oXG);
  float* as_    = ws + oAs;
  float* ad_    = ws + oAd;
  float* Wcat   = ws + oW;
  float* bias   = ws + oBias;
  float* pmax   = ws + oPmax;
  float* psum   = ws + oPsum;
  int*   gend   = (int*)(ws + oGend);
  int*   deg    = (int*)(ws + oDeg);
  int*   fill   = (int*)(ws + oFill);
  int*   gstart = (int*)(ws + oGstart);
  int*   off    = (int*)(ws + oOff);
  int*   tsum   = (int*)(ws + oTsum);
  int*   tbase  = (int*)(ws + oTbase);
  int*   sorted = (int*)(ws + oSorted);

  size_t zeroFloats = oGstart - oPmax;   // pmax,psum,gend,deg,fill
  hipMemsetAsync(pmax, 0, zeroFloats * sizeof(float), stream);
  hipMemsetAsync(gstart, 0x7f, G * sizeof(int), stream);

  pack_w_k<<<(64 * 832 + 832 + 255) / 256, 256, 0, stream>>>(
      skip_film_W, skip_W, film_lin_W, film_film_W, gat_W,
      skip_film_b, film_film_b, Wcat, bias);
  gemm_k<<<dim3((NN + 63) / 64, 7), 256, 0, stream>>>(x, Wcat, bias, Y);
  post_k<<<(NN + 3) / 4, 256, 0, stream>>>(Y, att_src, att_dst, as_, ad_, XG);
  count_k<<<(EE + 255) / 256, 256, 0, stream>>>(edge_index, deg);
  scanA_k<<<NT, 256, 0, stream>>>(deg, off, tsum);
  scanB_k<<<1, 256, 0, stream>>>(tsum, tbase, off);
  scanC_k<<<NT, 256, 0, stream>>>(off, tbase);
  scatter_k<<<(EE + 255) / 256, 256, 0, stream>>>(edge_index, edge_type,
                                                  off, fill, sorted);
  dst_k<<<NN / 4, 256, 0, stream>>>(sorted, off, Y, XG, as_, ad_,
                                    gat_b, graph_batch, gstart, gend);
  pool_k<<<dim3(GG, 8), 128, 0, stream>>>(Y, gstart, gend, pmax, psum);
  head_k<<<GG, 64, 0, stream>>>(pmax, psum, gstart, gend,
                                lin_W, lin_b, fc_W, fc_b, out);
}